// Round 10
// baseline (147.517 us; speedup 1.0000x reference)
//
#include <hip/hip_runtime.h>
#include <hip/hip_bf16.h>

typedef short bf16x8 __attribute__((ext_vector_type(8)));
typedef float f32x4 __attribute__((ext_vector_type(4)));

#define T_LEN 512
#define BATCH 32
#define D 512
#define M_TOT (T_LEN * BATCH) /* 16384 */
#define NLAYER 4

/* ---- layer-0 GEMM (fp32 A, proven round-7 structure) ---- */
#define BM 128
#define BN 128
#define BK 64
#define NT (D / BK) /* 8 K-tiles */
#define EP 72

/* ---- resident-B GEMM (layers 1-3): A direct-to-register ---- */
#define QBN 64   /* output cols per block (B panel 64KB LDS) */
#define QBM 512  /* 8 waves x 64 private rows */
#define QEP 72   /* epilogue LDS row stride */

#define CH 32            /* scan chunk length */
#define NCH (T_LEN / CH) /* 16 chunks */

// ---------------- fp32 -> bf16 convert (W only) ----------------
__global__ __launch_bounds__(256) void convert_k(const float* __restrict__ W,
                                                 __hip_bfloat16* __restrict__ Wb) {
    const int i = (blockIdx.x * 256 + threadIdx.x) * 4; // n = 1048576, exact
    float4 v = *(const float4*)(W + i);
    __hip_bfloat16 h0 = __float2bfloat16(v.x);
    __hip_bfloat16 h1 = __float2bfloat16(v.y);
    __hip_bfloat16 h2 = __float2bfloat16(v.z);
    __hip_bfloat16 h3 = __float2bfloat16(v.w);
    ushort4 o;
    o.x = *(const unsigned short*)&h0;
    o.y = *(const unsigned short*)&h1;
    o.z = *(const unsigned short*)&h2;
    o.w = *(const unsigned short*)&h3;
    *(ushort4*)(Wb + i) = o;
}

// ---------------- layer-0 GEMM: A fp32 (raw x), reg-staged convert ----------
// 128x128 tile, 4 waves, 2-phase dbuf, chunk-XOR swizzle, XCD swizzle,
// LDS-staged coalesced epilogue. Proven round-7 structure, unchanged.
__global__ __launch_bounds__(256) void gemm_l0(const float* __restrict__ Agf0,
                                               const __hip_bfloat16* __restrict__ Bt,
                                               const float* __restrict__ bias,
                                               __hip_bfloat16* __restrict__ Cb) {
    constexpr int K = D;
    constexpr int N = D;
    __shared__ __hip_bfloat16 smem[4 * BM * BK]; // 64KB
    __hip_bfloat16* const AsP[2] = {smem, smem + BM * BK};
    __hip_bfloat16* const BsP[2] = {smem + 2 * BM * BK, smem + 3 * BM * BK};

    const int tid  = threadIdx.x;
    const int wave = tid >> 6;
    const int lane = tid & 63;

    const int bid = blockIdx.x;
    const int xcd = bid & 7;
    const int jb  = bid >> 3;
    const int bm  = xcd * 16 + (jb >> 2);
    const int bn  = jb & 3;

    const int wm = (wave >> 1) * 64;
    const int wn = (wave & 1) * 64;

    const int srow = lane >> 3;
    const int scol = ((lane & 7) ^ srow) * 8;

    const float* Agf = Agf0 + (size_t)(bm * BM) * K;
    const __hip_bfloat16* Bg = Bt + (size_t)(bn * BN) * K;

    f32x4 acc[4][4] = {};
    float4 va[4][2];

#define STAGE_B0(buf, k0)                                                                            \
    do {                                                                                             \
        _Pragma("unroll") for (int jj = 0; jj < 4; ++jj) {                                           \
            const int rbase = (jj * 4 + wave) * 8;                                                   \
            __builtin_amdgcn_global_load_lds(                                                        \
                (const __attribute__((address_space(1))) void*)(Bg + (size_t)(rbase + srow) * K + (k0) + scol), \
                (__attribute__((address_space(3))) void*)(&BsP[buf][rbase * BK]), 16, 0, 0);         \
        }                                                                                            \
    } while (0)

#define LOAD_A0(k0)                                                                                  \
    do {                                                                                             \
        _Pragma("unroll") for (int jj = 0; jj < 4; ++jj) {                                           \
            const int rbase = (jj * 4 + wave) * 8;                                                   \
            const float* s = Agf + (size_t)(rbase + srow) * K + (k0) + scol;                         \
            va[jj][0] = *(const float4*)s;                                                           \
            va[jj][1] = *(const float4*)(s + 4);                                                     \
        }                                                                                            \
    } while (0)

#define WRITE_A0(buf)                                                                                \
    do {                                                                                             \
        _Pragma("unroll") for (int jj = 0; jj < 4; ++jj) {                                           \
            const int rbase = (jj * 4 + wave) * 8;                                                   \
            bf16x8 pk;                                                                               \
            _Pragma("unroll") for (int q = 0; q < 4; ++q) {                                          \
                __hip_bfloat16 t0 = __float2bfloat16(((const float*)&va[jj][0])[q]);                 \
                __hip_bfloat16 t1 = __float2bfloat16(((const float*)&va[jj][1])[q]);                 \
                pk[q]     = *(const short*)&t0;                                                      \
                pk[q + 4] = *(const short*)&t1;                                                      \
            }                                                                                        \
            *(bf16x8*)(&AsP[buf][(rbase + srow) * BK + (lane & 7) * 8]) = pk;                        \
        }                                                                                            \
    } while (0)

#define COMPUTE0(buf)                                                                                \
    do {                                                                                             \
        bf16x8 af[4][2], bv[4][2];                                                                   \
        const int fr = lane & 15;                                                                    \
        const int kq = lane >> 4;                                                                    \
        _Pragma("unroll") for (int mi = 0; mi < 4; ++mi) {                                           \
            const int r = wm + mi * 16 + fr;                                                         \
            _Pragma("unroll") for (int kh = 0; kh < 2; ++kh) {                                       \
                const int c = ((kh * 4 + kq) ^ (fr & 7)) * 8;                                        \
                af[mi][kh] = *(const bf16x8*)(&AsP[buf][r * BK + c]);                                \
            }                                                                                        \
        }                                                                                            \
        _Pragma("unroll") for (int ni = 0; ni < 4; ++ni) {                                           \
            const int r = wn + ni * 16 + fr;                                                         \
            _Pragma("unroll") for (int kh = 0; kh < 2; ++kh) {                                       \
                const int c = ((kh * 4 + kq) ^ (fr & 7)) * 8;                                        \
                bv[ni][kh] = *(const bf16x8*)(&BsP[buf][r * BK + c]);                                \
            }                                                                                        \
        }                                                                                            \
        _Pragma("unroll") for (int kh = 0; kh < 2; ++kh)                                             \
            _Pragma("unroll") for (int mi = 0; mi < 4; ++mi)                                         \
                _Pragma("unroll") for (int ni = 0; ni < 4; ++ni)                                     \
                    acc[mi][ni] = __builtin_amdgcn_mfma_f32_16x16x32_bf16(af[mi][kh], bv[ni][kh],    \
                                                                          acc[mi][ni], 0, 0, 0);    \
    } while (0)

    LOAD_A0(0);
    STAGE_B0(0, 0);
    WRITE_A0(0);
    __syncthreads();
    int cur = 0;
#pragma unroll
    for (int kt = 1; kt < NT; ++kt) {
        LOAD_A0(kt * BK);
        STAGE_B0(cur ^ 1, kt * BK);
        COMPUTE0(cur);
        WRITE_A0(cur ^ 1);
        __syncthreads();
        cur ^= 1;
    }
    COMPUTE0(cur);
    __syncthreads();

    {
        __hip_bfloat16* S = smem + wave * (64 * EP);
        const int cfr = lane & 15;
        const int cfq = lane >> 4;
        float bs[4];
#pragma unroll
        for (int ni = 0; ni < 4; ++ni) bs[ni] = bias[bn * BN + wn + ni * 16 + cfr];
#pragma unroll
        for (int mi = 0; mi < 4; ++mi)
#pragma unroll
            for (int ni = 0; ni < 4; ++ni)
#pragma unroll
                for (int r = 0; r < 4; ++r)
                    S[(mi * 16 + cfq * 4 + r) * EP + ni * 16 + cfr] =
                        __float2bfloat16(acc[mi][ni][r] + bs[ni]);
        const int rq = lane >> 3;
        const int cl = (lane & 7) * 8;
#pragma unroll
        for (int p = 0; p < 8; ++p) {
            const int lr = p * 8 + rq;
            bf16x8 v = *(const bf16x8*)(S + lr * EP + cl);
            *(bf16x8*)(&Cb[(size_t)(bm * BM + wm + lr) * N + bn * BN + wn + cl]) = v;
        }
    }
#undef STAGE_B0
#undef LOAD_A0
#undef WRITE_A0
#undef COMPUTE0
}

// ---------------- resident-B GEMM (layers 1-3), A direct-to-register --------
// Block = 512 thr (8 waves), tile 512x64, grid 256 = 1 block/CU.
// B panel (64x512 = 64KB, chunk-XOR swizzled) staged ONCE into LDS.
// A fragments load straight from global INTO MFMA fragment layout
// (lane row = lane&15, 16B at kq*8; lanes {l,l+16,l+32,l+48} = one 64B line),
// 3-slot rotation issued 2 K-tiles ahead, compiler-counted vmcnt waits.
// Per wave per K-tile: 8 ds_read_b128 (B only, ~96cy) vs 32 MFMA (~155cy)
// -> MFMA-bound. sched_barrier(0) per iter stops the unroll from hoisting
// all A loads (register-blowup guard). Accumulation order (t,kh,mi,ni)
// identical to prior rounds -> bitwise-identical output.
__global__ __launch_bounds__(512) void gemm_resB(const __hip_bfloat16* __restrict__ A,
                                                 const __hip_bfloat16* __restrict__ Bt,
                                                 const float* __restrict__ bias,
                                                 __hip_bfloat16* __restrict__ Cb) {
    constexpr int K = D;
    constexpr int N = D;
    __shared__ __hip_bfloat16 Bsm[QBN * D]; // 64KB resident B (+epilogue overlay)

    const int tid  = threadIdx.x;
    const int wave = tid >> 6;
    const int lane = tid & 63;

    // XCD swizzle: 256 blocks = 8 XCDs x (4 bm x 8 bn): per XCD, 4 A-panels
    // (2MB) + B (0.5MB) are L2-resident.
    const int bid = blockIdx.x;
    const int xcd = bid & 7;
    const int jb  = bid >> 3;            // 0..31
    const int bm  = xcd * 4 + (jb >> 3); // 0..31
    const int bn  = jb & 7;              // 0..7

    const __hip_bfloat16* Bg  = Bt + (size_t)(bn * QBN) * K;
    const __hip_bfloat16* Agw = A + (size_t)(bm * QBM + wave * 64) * K;

    const int fr = lane & 15;
    const int kq = lane >> 4;

    // ---- prologue: stage resident B (1 row = 1KB per gload_lds) -----------
#pragma unroll
    for (int jj = 0; jj < 8; ++jj) {
        const int row = wave * 8 + jj; // row & 7 == jj
        const int sc  = ((lane & ~7) | ((lane & 7) ^ (row & 7))) * 8; // pre-swizzled src
        __builtin_amdgcn_global_load_lds(
            (const __attribute__((address_space(1))) void*)(Bg + (size_t)row * K + sc),
            (__attribute__((address_space(3))) void*)(Bsm + row * D), 16, 0, 0);
    }

    bf16x8 ap[3][4][2]; // 3-slot A pipeline (full unroll -> static indices)
    f32x4 acc[4][4] = {};

#define LOADA(slot, t)                                                                               \
    do {                                                                                             \
        _Pragma("unroll") for (int mi = 0; mi < 4; ++mi)                                             \
            _Pragma("unroll") for (int kh = 0; kh < 2; ++kh)                                         \
                ap[slot][mi][kh] = *(const bf16x8*)(Agw + (size_t)(mi * 16 + fr) * K +               \
                                                    (t) * BK + kh * 32 + kq * 8);                    \
    } while (0)

    LOADA(0, 0);
    LOADA(1, 1);
    __syncthreads(); // B published (drains prologue loads too)

#pragma unroll
    for (int t = 0; t < NT; ++t) {
        __builtin_amdgcn_sched_barrier(0); // keep loads 2-ahead, no mass hoist
        if (t + 2 < NT) LOADA((t + 2) % 3, t + 2);
        bf16x8 bv[4][2];
#pragma unroll
        for (int ni = 0; ni < 4; ++ni)
#pragma unroll
            for (int kh = 0; kh < 2; ++kh) {
                const int r = ni * 16 + fr;
                const int c = t * BK + (((kh * 4 + kq) ^ (fr & 7)) * 8);
                bv[ni][kh] = *(const bf16x8*)(&Bsm[r * D + c]);
            }
        __builtin_amdgcn_s_setprio(1);
#pragma unroll
        for (int kh = 0; kh < 2; ++kh)
#pragma unroll
            for (int mi = 0; mi < 4; ++mi)
#pragma unroll
                for (int ni = 0; ni < 4; ++ni)
                    acc[mi][ni] = __builtin_amdgcn_mfma_f32_16x16x32_bf16(
                        ap[t % 3][mi][kh], bv[ni][kh], acc[mi][ni], 0, 0, 0);
        __builtin_amdgcn_s_setprio(0);
    }
#undef LOADA

    __syncthreads(); // all B reads done: safe to overlay Bsm with epilogue tiles

    // ---- epilogue: per-wave 64x64 tile in two 32-row halves (overlay B) ----
    // C/D layout: col=lane&15, row=(lane>>4)*4 + r  [m89-verified]
    {
        __hip_bfloat16* S = Bsm + wave * (32 * QEP); // 8 x 4.6KB = 37KB < 64KB
        const int cfq = lane >> 4;
        float bs[4];
#pragma unroll
        for (int ni = 0; ni < 4; ++ni) bs[ni] = bias[bn * QBN + ni * 16 + fr];
#pragma unroll
        for (int h = 0; h < 2; ++h) {
#pragma unroll
            for (int mi2 = 0; mi2 < 2; ++mi2) {
                const int mi = h * 2 + mi2;
#pragma unroll
                for (int ni = 0; ni < 4; ++ni)
#pragma unroll
                    for (int r = 0; r < 4; ++r)
                        S[(mi2 * 16 + cfq * 4 + r) * QEP + ni * 16 + fr] =
                            __float2bfloat16(acc[mi][ni][r] + bs[ni]);
            }
            const int rq = lane >> 3;      // 0..7
            const int cl = (lane & 7) * 8; // 0..56
#pragma unroll
            for (int p = 0; p < 4; ++p) {
                const int lr = p * 8 + rq;
                bf16x8 v = *(const bf16x8*)(S + lr * QEP + cl);
                *(bf16x8*)(&Cb[(size_t)(bm * QBM + wave * 64 + h * 32 + lr) * N +
                               bn * QBN + cl]) = v;
            }
        }
    }
}

// ---------------- fused parallel scan: h_t = max(0, a_t + u*h_{t-1}) ---------
// Chunk decomposition (h>=0 domain): F_c(h) = max(m, d + e*h), e = u^CH.
template <int MODE>
__global__ __launch_bounds__(512) void scan_k(const __hip_bfloat16* __restrict__ xh,
                                              const float* __restrict__ u,
                                              float* __restrict__ outf,
                                              __hip_bfloat16* __restrict__ outb) {
    __shared__ float4 md[NCH][32];
    const int i2  = threadIdx.x & 31;
    const int c   = threadIdx.x >> 5; // 0..15
    const int idx = blockIdx.x * 64 + i2 * 2;
    const float u0 = u[idx & (D - 1)];
    const float u1 = u[(idx + 1) & (D - 1)];

    const __hip_bfloat16* p = xh + (size_t)c * CH * M_TOT + idx;
    unsigned int xv[CH];
#pragma unroll
    for (int t = 0; t < CH; ++t) xv[t] = *(const unsigned int*)(p + (size_t)t * M_TOT);

    float m0 = 0.f, d0 = 0.f, m1 = 0.f, d1 = 0.f;
#pragma unroll
    for (int t = 0; t < CH; ++t) {
        const float a0 = __uint_as_float(xv[t] << 16);
        const float a1 = __uint_as_float(xv[t] & 0xffff0000u);
        m0 = fmaxf(fmaf(u0, m0, a0), 0.f);
        d0 = fmaf(u0, d0, a0);
        m1 = fmaxf(fmaf(u1, m1, a1), 0.f);
        d1 = fmaf(u1, d1, a1);
    }
    md[c][i2] = make_float4(m0, d0, m1, d1);
    __syncthreads();

    float e0 = u0 * u0, e1 = u1 * u1;       // u^2
    e0 *= e0; e0 *= e0; e0 *= e0; e0 *= e0; // u^32 == u^CH
    e1 *= e1; e1 *= e1; e1 *= e1; e1 *= e1;
    float h0 = 0.f, h1 = 0.f;
    for (int jj = 0; jj < c; ++jj) {
        const float4 v = md[jj][i2];
        h0 = fmaxf(v.x, fmaf(e0, h0, v.y));
        h1 = fmaxf(v.z, fmaf(e1, h1, v.w));
    }

    const size_t base = (size_t)c * CH * M_TOT + idx;
#pragma unroll
    for (int t = 0; t < CH; ++t) {
        const size_t off = base + (size_t)t * M_TOT;
        const float a0 = __uint_as_float(xv[t] << 16);
        const float a1 = __uint_as_float(xv[t] & 0xffff0000u);
        h0 = fmaxf(fmaf(u0, h0, a0), 0.f);
        h1 = fmaxf(fmaf(u1, h1, a1), 0.f);
        if (MODE & 1) *(float2*)(outf + off) = make_float2(h0, h1);
        if (MODE & 2) {
            __hip_bfloat16 b0 = __float2bfloat16(h0);
            __hip_bfloat16 b1 = __float2bfloat16(h1);
            unsigned int pk = (unsigned int)(*(unsigned short*)&b0) |
                              ((unsigned int)(*(unsigned short*)&b1) << 16);
            *(unsigned int*)(outb + off) = pk;
        }
    }
}

extern "C" void kernel_launch(void* const* d_in, const int* in_sizes, int n_in,
                              void* d_out, int out_size, void* d_ws, size_t ws_size,
                              hipStream_t stream) {
    const float* x = (const float*)d_in[0]; // [T, B, Din]
    const float* W = (const float*)d_in[1]; // [L, Dh, Din]
    const float* b = (const float*)d_in[2]; // [L, Dh]
    const float* u = (const float*)d_in[3]; // [L, Dh]
    float* out = (float*)d_out;             // [T, B, Dh]

    __hip_bfloat16* Wb = (__hip_bfloat16*)d_ws;                                       // 2 MB
    __hip_bfloat16* Ab = (__hip_bfloat16*)((char*)d_ws + (size_t)NLAYER * D * D * 2); // 16.8 MB
    __hip_bfloat16* Xh = Ab + (size_t)M_TOT * D;                                      // 16.8 MB

    convert_k<<<(NLAYER * D * D / 4) / 256, 256, 0, stream>>>(W, Wb);

    for (int l = 0; l < NLAYER; ++l) {
        if (l == 0) {
            gemm_l0<<<(M_TOT / BM) * (D / BN), 256, 0, stream>>>(x, Wb, b, Xh);
        } else {
            gemm_resB<<<(M_TOT / QBM) * (D / QBN), 512, 0, stream>>>(
                Ab, Wb + (size_t)l * D * D, b + (size_t)l * D, Xh);
        }
        if (l < NLAYER - 1) {
            scan_k<2><<<M_TOT / 64, 512, 0, stream>>>(Xh, u + (size_t)l * D, nullptr, Ab);
        } else {
            scan_k<1><<<M_TOT / 64, 512, 0, stream>>>(Xh, u + (size_t)l * D, out, nullptr);
        }
    }
}